// Round 12
// baseline (117910.889 us; speedup 1.0000x reference)
//
#include <hip/hip_runtime.h>
#include <hip/hip_bf16.h>

#define BB 16
#define DEPTH 24
#define DM 192
#define DI 384
#define DS 16
#define DC 4
#define DTR 12
#define LL 320
#define NX 256
#define NZ 64
#define NT (BB * LL)
#define EPSV 1e-5f

__device__ inline float siluf(float x) { return x / (1.f + expf(-x)); }
__device__ inline float softplusf(float x) {
    return (x > 20.f) ? x : log1pf(expf(x));
}

// ---------- zero a buffer ----------
__global__ void zero_kernel(float* p, int n) {
    int i = blockIdx.x * blockDim.x + threadIdx.x;
    if (i < n) p[i] = 0.f;
}

// ---------- patch embed: one thread per (b, t, d), cross-correlation ----------
__global__ void patch_embed_naive(const float* img, const float* w,
                                  const float* bias, const float* pos,
                                  float* hidden, int side, int tok_off) {
    int idx = blockIdx.x * blockDim.x + threadIdx.x;
    int ntok = side * side;
    if (idx >= BB * ntok * DM) return;
    int d = idx % DM;
    int t = (idx / DM) % ntok;
    int b = idx / (DM * ntok);
    int ph = t / side, pw = t % side;
    int S = side * 16;
    float acc = bias[d];
    for (int c = 0; c < 3; c++)
        for (int i = 0; i < 16; i++)
            for (int j = 0; j < 16; j++)
                acc += img[((size_t)(b * 3 + c) * S + ph * 16 + i) * S + pw * 16 + j]
                     * w[((size_t)d * 3 + c) * 256 + i * 16 + j];
    acc += pos[(size_t)t * DM + d];
    hidden[((size_t)b * LL + tok_off + t) * DM + d] = acc;
}

// ---------- add + LN prenorm: one thread per token ----------
__global__ void addnorm_naive(const float* hidden, float* residual, float* hn,
                              const float* w, const float* bias, int layer) {
    int t = blockIdx.x * blockDim.x + threadIdx.x;
    if (t >= NT) return;
    size_t base = (size_t)t * DM;
    float mu = 0.f;
    for (int d = 0; d < DM; d++) {
        float v = residual[base + d] + hidden[base + d];
        residual[base + d] = v;
        mu += v;
    }
    mu /= DM;
    float var = 0.f;
    for (int d = 0; d < DM; d++) {
        float v = residual[base + d] - mu;
        var += v * v;
    }
    var /= DM;
    float inv = rsqrtf(var + EPSV);
    for (int d = 0; d < DM; d++)
        hn[base + d] = (residual[base + d] - mu) * inv * w[layer * DM + d]
                     + bias[layer * DM + d];
}

// ---------- naive GEMM: out[t,j] = sum_k x[t,k]*w[woff+j*K+k] ----------
__global__ void gemm_naive(const float* x, const float* w, float* out,
                           int N, int K, size_t woff) {
    int idx = blockIdx.x * blockDim.x + threadIdx.x;
    if (idx >= NT * N) return;
    int j = idx % N;
    int t = idx / N;
    const float* wr = w + woff + (size_t)j * K;
    const float* xr = x + (size_t)t * K;
    float acc = 0.f;
    for (int k = 0; k < K; k++) acc += xr[k] * wr[k];
    out[(size_t)t * N + j] = acc;
}

// ---------- causal depthwise conv (cross-correlation, pad-left 3) + silu ----------
__global__ void conv_silu_naive(const float* xz, const float* cw, const float* cb,
                                float* xc, int layer) {
    int idx = blockIdx.x * blockDim.x + threadIdx.x;
    if (idx >= NT * DI) return;
    int d = idx % DI;
    int t = idx / DI;
    int l = t % LL;
    float acc = cb[layer * DI + d];
    for (int k = 0; k < DC; k++) {
        int li = l - 3 + k;
        if (li >= 0)
            acc += cw[(size_t)layer * DI * DC + d * DC + k]
                 * xz[(size_t)(t - 3 + k) * (2 * DI) + d];
    }
    xc[idx] = siluf(acc);
}

// ---------- dt = softplus(dbl[:, :12] @ dt_w.T + dt_b) ----------
__global__ void dt_naive(const float* dbl, const float* dtw, const float* dtb,
                         float* dt, int layer) {
    int idx = blockIdx.x * blockDim.x + threadIdx.x;
    if (idx >= NT * DI) return;
    int d = idx % DI;
    int t = idx / DI;
    float acc = dtb[layer * DI + d];
    for (int r = 0; r < DTR; r++)
        acc += dbl[(size_t)t * 44 + r] * dtw[(size_t)layer * DI * DTR + d * DTR + r];
    dt[idx] = softplusf(acc);
}

// ---------- SSM scan: one thread per (b, d), 16 states in registers ----------
__global__ void scan_naive(const float* dt, const float* xc, const float* dbl,
                           const float* xz, const float* A_log, const float* Dskip,
                           float* y, int layer) {
    int g = blockIdx.x * blockDim.x + threadIdx.x;
    if (g >= BB * DI) return;
    int b = g / DI, d = g % DI;
    float A[DS], h[DS];
    for (int n = 0; n < DS; n++) {
        A[n] = -expf(A_log[(size_t)layer * DI * DS + d * DS + n]);
        h[n] = 0.f;
    }
    float Dv = Dskip[layer * DI + d];
    for (int l = 0; l < LL; l++) {
        size_t t = (size_t)b * LL + l;
        float dtv = dt[t * DI + d];
        float xcv = xc[t * DI + d];
        float p = 0.f;
        for (int n = 0; n < DS; n++) {
            float Bv = dbl[t * 44 + DTR + n];
            float Cv = dbl[t * 44 + DTR + DS + n];
            h[n] = expf(dtv * A[n]) * h[n] + dtv * Bv * xcv;
            p += h[n] * Cv;
        }
        float zg = xz[t * (2 * DI) + DI + d];
        y[t * DI + d] = (p + xcv * Dv) * siluf(zg);
    }
}

// ---------- final: LN(residual+hidden) -> FLOAT32 output ----------
__global__ void final_naive(const float* hidden, const float* residual,
                            const float* w, const float* bias, float* out) {
    int t = blockIdx.x * blockDim.x + threadIdx.x;
    if (t >= NT) return;
    size_t base = (size_t)t * DM;
    float mu = 0.f;
    for (int d = 0; d < DM; d++) mu += residual[base + d] + hidden[base + d];
    mu /= DM;
    float var = 0.f;
    for (int d = 0; d < DM; d++) {
        float v = residual[base + d] + hidden[base + d] - mu;
        var += v * v;
    }
    var /= DM;
    float inv = rsqrtf(var + EPSV);
    for (int d = 0; d < DM; d++) {
        float v = residual[base + d] + hidden[base + d] - mu;
        out[base + d] = v * inv * w[d] + bias[d];
    }
}

extern "C" void kernel_launch(void* const* d_in, const int* in_sizes, int n_in,
                              void* d_out, int out_size, void* d_ws, size_t ws_size,
                              hipStream_t stream) {
    const float* x_img   = (const float*)d_in[0];
    const float* z_img   = (const float*)d_in[1];
    const float* patch_w = (const float*)d_in[2];
    const float* patch_b = (const float*)d_in[3];
    const float* pos_x   = (const float*)d_in[4];
    const float* pos_z   = (const float*)d_in[5];
    const float* ln_w    = (const float*)d_in[6];
    const float* ln_b    = (const float*)d_in[7];
    const float* in_w    = (const float*)d_in[8];
    const float* conv_w  = (const float*)d_in[9];
    const float* conv_b  = (const float*)d_in[10];
    const float* xproj_w = (const float*)d_in[11];
    const float* dt_w    = (const float*)d_in[12];
    const float* dt_b    = (const float*)d_in[13];
    const float* A_log   = (const float*)d_in[14];
    const float* D_skip  = (const float*)d_in[15];
    const float* out_w   = (const float*)d_in[16];
    const float* fnorm_w = (const float*)d_in[17];
    const float* fnorm_b = (const float*)d_in[18];

    float* hidden   = (float*)d_ws;                       // NT*DM
    float* residual = hidden   + (size_t)NT * DM;         // NT*DM
    float* hn       = residual + (size_t)NT * DM;         // NT*DM
    float* xz       = hn       + (size_t)NT * DM;         // NT*768
    float* xc       = xz       + (size_t)NT * 2 * DI;     // NT*DI
    float* dbl      = xc       + (size_t)NT * DI;         // NT*44
    float* dtb      = dbl      + (size_t)NT * 44;         // NT*DI
    float* yb       = dtb      + (size_t)NT * DI;         // NT*DI

    zero_kernel<<<(NT * DM + 255) / 256, 256, 0, stream>>>(residual, NT * DM);

    // z-first concat: z tokens 0..63, x tokens 64..319
    patch_embed_naive<<<(BB * NX * DM + 255) / 256, 256, 0, stream>>>(
        x_img, patch_w, patch_b, pos_x, hidden, 16, NZ);
    patch_embed_naive<<<(BB * NZ * DM + 255) / 256, 256, 0, stream>>>(
        z_img, patch_w, patch_b, pos_z, hidden, 8, 0);

    for (int i = 0; i < DEPTH; i++) {
        addnorm_naive<<<(NT + 63) / 64, 64, 0, stream>>>(
            hidden, residual, hn, ln_w, ln_b, i);
        gemm_naive<<<(NT * 768 + 255) / 256, 256, 0, stream>>>(
            hn, in_w, xz, 768, 192, (size_t)i * 768 * 192);
        conv_silu_naive<<<(NT * DI + 255) / 256, 256, 0, stream>>>(
            xz, conv_w, conv_b, xc, i);
        gemm_naive<<<(NT * 44 + 255) / 256, 256, 0, stream>>>(
            xc, xproj_w, dbl, 44, 384, (size_t)i * 44 * 384);
        dt_naive<<<(NT * DI + 255) / 256, 256, 0, stream>>>(
            dbl, dt_w, dt_b, dtb, i);
        scan_naive<<<(BB * DI + 63) / 64, 64, 0, stream>>>(
            dtb, xc, dbl, xz, A_log, D_skip, yb, i);
        gemm_naive<<<(NT * 192 + 255) / 256, 256, 0, stream>>>(
            yb, out_w, hidden, 192, 384, (size_t)i * 192 * 384);
    }

    final_naive<<<(NT + 63) / 64, 64, 0, stream>>>(
        hidden, residual, fnorm_w, fnorm_b, (float*)d_out);
}

// Round 13
// 10714.001 us; speedup vs baseline: 11.0053x; 11.0053x over previous
//
#include <hip/hip_runtime.h>
#include <hip/hip_bf16.h>

#define BB 16
#define DEPTH 24
#define DM 192
#define DI 384
#define DS 16
#define DC 4
#define DTR 12
#define LL 320
#define NX 256
#define NZ 64
#define NT (BB * LL)
#define EPSV 1e-5f

__device__ inline float siluf(float x) { return x / (1.f + __expf(-x)); }
__device__ inline float softplusf(float x) {
    return (x > 20.f) ? x : log1pf(expf(x));
}
__device__ inline float wave_sum64(float v) {
    #pragma unroll
    for (int o = 32; o > 0; o >>= 1) v += __shfl_xor(v, o);
    return v;
}

// ---------- zero a buffer ----------
__global__ void zero_kernel(float* p, int n) {
    int i = blockIdx.x * blockDim.x + threadIdx.x;
    if (i < n) p[i] = 0.f;
}

// ---------- patch embed: one block per (b, patch); img patch staged in LDS ----------
__global__ __launch_bounds__(192) void patch_embed_tile(const float* __restrict__ img,
                                                        const float* __restrict__ w,
                                                        const float* __restrict__ bias,
                                                        const float* __restrict__ pos,
                                                        float* __restrict__ hidden,
                                                        int side, int tok_off) {
    __shared__ float sp[768];
    int bt = blockIdx.x;
    int ntok = side * side;
    int t = bt % ntok;
    int b = bt / ntok;
    int ph = t / side, pw = t % side;
    int S = side * 16;
    for (int i = threadIdx.x; i < 768; i += 192) {
        int c = i >> 8;
        int p = i & 255;
        sp[i] = img[((size_t)(b * 3 + c) * S + ph * 16 + (p >> 4)) * S + pw * 16 + (p & 15)];
    }
    __syncthreads();
    int d = threadIdx.x;
    const float* wr = w + (size_t)d * 768;
    float acc = bias[d];
    for (int k = 0; k < 768; k += 4) {
        float4 wv = *(const float4*)(wr + k);
        acc += sp[k] * wv.x + sp[k + 1] * wv.y + sp[k + 2] * wv.z + sp[k + 3] * wv.w;
    }
    acc += pos[(size_t)t * DM + d];
    hidden[((size_t)b * LL + tok_off + t) * DM + d] = acc;
}

// ---------- add + LN prenorm: one wave per token ----------
__global__ __launch_bounds__(64) void addnorm_kernel(const float* __restrict__ hidden,
                                                     float* __restrict__ residual,
                                                     float* __restrict__ hn,
                                                     const float* __restrict__ w,
                                                     const float* __restrict__ bias,
                                                     size_t off) {
    int t = blockIdx.x;
    int lane = threadIdx.x;
    size_t base = (size_t)t * DM;
    float a = residual[base + lane]       + hidden[base + lane];
    float b = residual[base + 64 + lane]  + hidden[base + 64 + lane];
    float c = residual[base + 128 + lane] + hidden[base + 128 + lane];
    residual[base + lane] = a;
    residual[base + 64 + lane] = b;
    residual[base + 128 + lane] = c;
    float mu = wave_sum64(a + b + c) * (1.f / 192.f);
    float va = a - mu, vb = b - mu, vc = c - mu;
    float var = wave_sum64(va * va + vb * vb + vc * vc) * (1.f / 192.f);
    float inv = rsqrtf(var + EPSV);
    hn[base + lane]       = va * inv * w[off + lane]       + bias[off + lane];
    hn[base + 64 + lane]  = vb * inv * w[off + 64 + lane]  + bias[off + 64 + lane];
    hn[base + 128 + lane] = vc * inv * w[off + 128 + lane] + bias[off + 128 + lane];
}

// ---------- token-tiled GEMM: out[t,j] = sum_k x[t,k]*w[woff + j*K + k] ----------
template<int TT, int N, int K, int BLK>
__global__ __launch_bounds__(BLK) void gemm_tok(const float* __restrict__ x,
                                                const float* __restrict__ w,
                                                size_t woff,
                                                float* __restrict__ out) {
    __shared__ float sh[TT * K];
    int t0 = blockIdx.x * TT;
    for (int idx = threadIdx.x; idx < TT * K; idx += BLK)
        sh[idx] = x[(size_t)t0 * K + idx];
    __syncthreads();
    for (int j = threadIdx.x; j < N; j += BLK) {
        const float* wr = w + woff + (size_t)j * K;
        float acc[TT];
        #pragma unroll
        for (int tt = 0; tt < TT; tt++) acc[tt] = 0.f;
        for (int k = 0; k < K; k += 4) {
            float4 wv = *(const float4*)(wr + k);
            #pragma unroll
            for (int tt = 0; tt < TT; tt++) {
                const float* s = sh + tt * K + k;
                acc[tt] += s[0] * wv.x + s[1] * wv.y + s[2] * wv.z + s[3] * wv.w;
            }
        }
        #pragma unroll
        for (int tt = 0; tt < TT; tt++)
            out[(size_t)(t0 + tt) * N + j] = acc[tt];
    }
}

// ---------- causal depthwise conv (cross-correlation, pad-left 3) + silu ----------
__global__ void conv_silu_kernel(const float* __restrict__ xz,
                                 const float* __restrict__ cw,
                                 const float* __restrict__ cb,
                                 size_t cwoff, size_t cboff,
                                 float* __restrict__ xc) {
    int idx = blockIdx.x * blockDim.x + threadIdx.x;
    if (idx >= NT * DI) return;
    int d = idx % DI;
    int t = idx / DI;
    int l = t % LL;
    float acc = cb[cboff + d];
    #pragma unroll
    for (int k = 0; k < DC; k++) {
        int li = l - 3 + k;
        if (li >= 0)
            acc += cw[cwoff + (size_t)d * DC + k]
                 * xz[(size_t)(t - 3 + k) * (2 * DI) + d];
    }
    xc[idx] = siluf(acc);
}

// ---------- dt = softplus(dbl[:, :12] @ dt_w.T + dt_b) ----------
__global__ void dt_kernel(const float* __restrict__ dbl,
                          const float* __restrict__ dtw,
                          const float* __restrict__ dtb,
                          size_t dtwoff, size_t dtboff,
                          float* __restrict__ dt) {
    int idx = blockIdx.x * blockDim.x + threadIdx.x;
    if (idx >= NT * DI) return;
    int d = idx % DI;
    int t = idx / DI;
    float acc = dtb[dtboff + d];
    const float* xr = dbl + (size_t)t * 44;
    #pragma unroll
    for (int r = 0; r < DTR; r++)
        acc += xr[r] * dtw[dtwoff + (size_t)d * DTR + r];
    dt[idx] = softplusf(acc);
}

// ---------- SSM scan: 16 lanes per (b,d), lane n = state n ----------
__global__ __launch_bounds__(256) void scan_kernel(const float* __restrict__ dt,
                                                   const float* __restrict__ xc,
                                                   const float* __restrict__ dbl,
                                                   const float* __restrict__ xz,
                                                   const float* __restrict__ A_log,
                                                   const float* __restrict__ Dskip,
                                                   size_t aoff, size_t doff,
                                                   float* __restrict__ y) {
    int g = blockIdx.x * 16 + (threadIdx.x >> 4);
    if (g >= BB * DI) return;
    int n = threadIdx.x & 15;
    int b = g / DI;
    int d = g % DI;
    float A = -expf(A_log[aoff + (size_t)d * DS + n]);
    float Dv = Dskip[doff + d];
    float h = 0.f;
    for (int l = 0; l < LL; l++) {
        size_t t = (size_t)b * LL + l;
        float dtv = dt[t * DI + d];
        float xcv = xc[t * DI + d];
        float Bv = dbl[t * 44 + DTR + n];
        float Cv = dbl[t * 44 + DTR + DS + n];
        h = expf(dtv * A) * h + dtv * Bv * xcv;
        float p = h * Cv;
        p += __shfl_xor(p, 1);
        p += __shfl_xor(p, 2);
        p += __shfl_xor(p, 4);
        p += __shfl_xor(p, 8);
        if (n == 0) {
            float zg = xz[t * (2 * DI) + DI + d];
            y[t * DI + d] = (p + xcv * Dv) * siluf(zg);
        }
    }
}

// ---------- final: LN(residual + hidden) -> float32, one wave per token ----------
__global__ __launch_bounds__(64) void final_kernel(const float* __restrict__ hidden,
                                                   const float* __restrict__ residual,
                                                   const float* __restrict__ w,
                                                   const float* __restrict__ bias,
                                                   float* __restrict__ out) {
    int t = blockIdx.x;
    int lane = threadIdx.x;
    size_t base = (size_t)t * DM;
    float a = residual[base + lane]       + hidden[base + lane];
    float b = residual[base + 64 + lane]  + hidden[base + 64 + lane];
    float c = residual[base + 128 + lane] + hidden[base + 128 + lane];
    float mu = wave_sum64(a + b + c) * (1.f / 192.f);
    float va = a - mu, vb = b - mu, vc = c - mu;
    float var = wave_sum64(va * va + vb * vb + vc * vc) * (1.f / 192.f);
    float inv = rsqrtf(var + EPSV);
    out[base + lane]       = va * inv * w[lane]       + bias[lane];
    out[base + 64 + lane]  = vb * inv * w[64 + lane]  + bias[64 + lane];
    out[base + 128 + lane] = vc * inv * w[128 + lane] + bias[128 + lane];
}

extern "C" void kernel_launch(void* const* d_in, const int* in_sizes, int n_in,
                              void* d_out, int out_size, void* d_ws, size_t ws_size,
                              hipStream_t stream) {
    const float* x_img   = (const float*)d_in[0];
    const float* z_img   = (const float*)d_in[1];
    const float* patch_w = (const float*)d_in[2];
    const float* patch_b = (const float*)d_in[3];
    const float* pos_x   = (const float*)d_in[4];
    const float* pos_z   = (const float*)d_in[5];
    const float* ln_w    = (const float*)d_in[6];
    const float* ln_b    = (const float*)d_in[7];
    const float* in_w    = (const float*)d_in[8];
    const float* conv_w  = (const float*)d_in[9];
    const float* conv_b  = (const float*)d_in[10];
    const float* xproj_w = (const float*)d_in[11];
    const float* dt_w    = (const float*)d_in[12];
    const float* dt_b    = (const float*)d_in[13];
    const float* A_log   = (const float*)d_in[14];
    const float* D_skip  = (const float*)d_in[15];
    const float* out_w   = (const float*)d_in[16];
    const float* fnorm_w = (const float*)d_in[17];
    const float* fnorm_b = (const float*)d_in[18];

    float* hidden   = (float*)d_ws;                       // NT*DM
    float* residual = hidden   + (size_t)NT * DM;         // NT*DM
    float* hn       = residual + (size_t)NT * DM;         // NT*DM
    float* xz       = hn       + (size_t)NT * DM;         // NT*768
    float* xc       = xz       + (size_t)NT * 2 * DI;     // NT*DI
    float* dbl      = xc       + (size_t)NT * DI;         // NT*44
    float* dtb      = dbl      + (size_t)NT * 44;         // NT*DI
    float* yb       = dtb      + (size_t)NT * DI;         // NT*DI

    zero_kernel<<<(NT * DM + 255) / 256, 256, 0, stream>>>(residual, NT * DM);

    // z-first concat: z tokens 0..63, x tokens 64..319
    patch_embed_tile<<<BB * NX, 192, 0, stream>>>(
        x_img, patch_w, patch_b, pos_x, hidden, 16, NZ);
    patch_embed_tile<<<BB * NZ, 192, 0, stream>>>(
        z_img, patch_w, patch_b, pos_z, hidden, 8, 0);

    for (int i = 0; i < DEPTH; i++) {
        addnorm_kernel<<<NT, 64, 0, stream>>>(
            hidden, residual, hn, ln_w, ln_b, (size_t)i * DM);
        gemm_tok<16, 768, 192, 256><<<NT / 16, 256, 0, stream>>>(
            hn, in_w, (size_t)i * 768 * 192, xz);
        conv_silu_kernel<<<(NT * DI + 255) / 256, 256, 0, stream>>>(
            xz, conv_w, conv_b, (size_t)i * DI * DC, (size_t)i * DI, xc);
        gemm_tok<16, 44, 384, 64><<<NT / 16, 64, 0, stream>>>(
            xc, xproj_w, (size_t)i * 44 * 384, dbl);
        dt_kernel<<<(NT * DI + 255) / 256, 256, 0, stream>>>(
            dbl, dt_w, dt_b, (size_t)i * DI * DTR, (size_t)i * DI, dtb);
        scan_kernel<<<(BB * DI + 15) / 16, 256, 0, stream>>>(
            dtb, xc, dbl, xz, A_log, D_skip,
            (size_t)i * DI * DS, (size_t)i * DI, yb);
        gemm_tok<16, 192, 384, 192><<<NT / 16, 192, 0, stream>>>(
            yb, out_w, (size_t)i * 192 * 384, hidden);
    }

    final_kernel<<<NT, 64, 0, stream>>>(hidden, residual, fnorm_w, fnorm_b,
                                        (float*)d_out);
}

// Round 14
// 8004.601 us; speedup vs baseline: 14.7304x; 1.3385x over previous
//
#include <hip/hip_runtime.h>
#include <hip/hip_bf16.h>

#define BB 16
#define DEPTH 24
#define DM 192
#define DI 384
#define DS 16
#define DC 4
#define DTR 12
#define LL 320
#define NX 256
#define NZ 64
#define NT (BB * LL)
#define NC 8          // scan chunks
#define LC 40         // chunk length
#define EPSV 1e-5f

__device__ inline float siluf(float x) { return x / (1.f + __expf(-x)); }
__device__ inline float softplusf(float x) {
    return (x > 20.f) ? x : log1pf(expf(x));
}
__device__ inline float wave_sum64(float v) {
    #pragma unroll
    for (int o = 32; o > 0; o >>= 1) v += __shfl_xor(v, o);
    return v;
}

// ---------- zero residual ----------
__global__ void zero_kernel(float* p, int n) {
    int i = blockIdx.x * blockDim.x + threadIdx.x;
    if (i < n) p[i] = 0.f;
}

// ---------- add + LN prenorm: one wave per token. hn aliases hidden ----------
__global__ __launch_bounds__(64) void addnorm_kernel(const float* hidden,
                                                     float* __restrict__ residual,
                                                     float* hn,
                                                     const float* __restrict__ w,
                                                     const float* __restrict__ bias,
                                                     size_t off) {
    int t = blockIdx.x;
    int lane = threadIdx.x;
    size_t base = (size_t)t * DM;
    float a = residual[base + lane]       + hidden[base + lane];
    float b = residual[base + 64 + lane]  + hidden[base + 64 + lane];
    float c = residual[base + 128 + lane] + hidden[base + 128 + lane];
    residual[base + lane] = a;
    residual[base + 64 + lane] = b;
    residual[base + 128 + lane] = c;
    float mu = wave_sum64(a + b + c) * (1.f / 192.f);
    float va = a - mu, vb = b - mu, vc = c - mu;
    float var = wave_sum64(va * va + vb * vb + vc * vc) * (1.f / 192.f);
    float inv = rsqrtf(var + EPSV);
    hn[base + lane]       = va * inv * w[off + lane]       + bias[off + lane];
    hn[base + 64 + lane]  = vb * inv * w[off + 64 + lane]  + bias[off + 64 + lane];
    hn[base + 128 + lane] = vc * inv * w[off + 128 + lane] + bias[off + 128 + lane];
}

// ---------- LDS-tiled GEMM: out[t0+tt, j0+j] = sum_k x[t,k]*w[woff+(j0+j)*K+k] ----------
// grid: (NT/16, N/64). LDS stride K_T+1=193 breaks the 192%32==0 bank pathology.
template<int K, int KT>
__global__ __launch_bounds__(256) void gemm_lds(const float* __restrict__ x,
                                                const float* __restrict__ w,
                                                size_t woff,
                                                float* __restrict__ out, int N) {
    __shared__ float xs[16 * (KT + 1)];
    __shared__ float ws[64 * (KT + 1)];
    int t0 = blockIdx.x * 16;
    int j0 = blockIdx.y * 64;
    int j  = threadIdx.x & 63;
    int tg = threadIdx.x >> 6;   // 0..3 -> tokens tg*4 .. tg*4+3
    float acc0 = 0.f, acc1 = 0.f, acc2 = 0.f, acc3 = 0.f;
    for (int kt = 0; kt < K; kt += KT) {
        for (int idx = threadIdx.x; idx < 16 * KT; idx += 256) {
            int tt = idx / KT, k = idx % KT;
            xs[tt * (KT + 1) + k] = x[(size_t)(t0 + tt) * K + kt + k];
        }
        for (int idx = threadIdx.x; idx < 64 * KT; idx += 256) {
            int jj = idx / KT, k = idx % KT;
            ws[jj * (KT + 1) + k] = w[woff + (size_t)(j0 + jj) * K + kt + k];
        }
        __syncthreads();
        const float* xr0 = xs + (tg * 4 + 0) * (KT + 1);
        const float* xr1 = xs + (tg * 4 + 1) * (KT + 1);
        const float* xr2 = xs + (tg * 4 + 2) * (KT + 1);
        const float* xr3 = xs + (tg * 4 + 3) * (KT + 1);
        const float* wr  = ws + j * (KT + 1);
        #pragma unroll 4
        for (int k = 0; k < KT; k++) {
            float wv = wr[k];
            acc0 += xr0[k] * wv;
            acc1 += xr1[k] * wv;
            acc2 += xr2[k] * wv;
            acc3 += xr3[k] * wv;
        }
        __syncthreads();
    }
    out[(size_t)(t0 + tg * 4 + 0) * N + j0 + j] = acc0;
    out[(size_t)(t0 + tg * 4 + 1) * N + j0 + j] = acc1;
    out[(size_t)(t0 + tg * 4 + 2) * N + j0 + j] = acc2;
    out[(size_t)(t0 + tg * 4 + 3) * N + j0 + j] = acc3;
}

// ---------- patch embed as im2col GEMM. grid: (B*ntok/16, 3) ----------
__global__ __launch_bounds__(256) void patch_gemm(const float* __restrict__ img,
                                                  const float* __restrict__ w,
                                                  const float* __restrict__ bias,
                                                  const float* __restrict__ pos,
                                                  float* __restrict__ hidden,
                                                  int side, int tok_off) {
    __shared__ float xs[16 * 193];
    __shared__ float ws[64 * 193];
    int ntok = side * side;
    int pt0 = blockIdx.x * 16;
    int j0 = blockIdx.y * 64;
    int S = side * 16;
    int j  = threadIdx.x & 63;
    int tg = threadIdx.x >> 6;
    float acc0 = 0.f, acc1 = 0.f, acc2 = 0.f, acc3 = 0.f;
    for (int kt = 0; kt < 768; kt += 192) {
        for (int idx = threadIdx.x; idx < 16 * 192; idx += 256) {
            int tt = idx / 192, kk = idx % 192;
            int k = kt + kk;
            int c = k >> 8, p = k & 255, pi = p >> 4, pj = p & 15;
            int patch = pt0 + tt;
            int b = patch / ntok, t = patch % ntok;
            int ph = t / side, pw = t % side;
            xs[tt * 193 + kk] =
                img[((size_t)(b * 3 + c) * S + ph * 16 + pi) * S + pw * 16 + pj];
        }
        for (int idx = threadIdx.x; idx < 64 * 192; idx += 256) {
            int jj = idx / 192, kk = idx % 192;
            ws[jj * 193 + kk] = w[(size_t)(j0 + jj) * 768 + kt + kk];
        }
        __syncthreads();
        const float* xr0 = xs + (tg * 4 + 0) * 193;
        const float* xr1 = xs + (tg * 4 + 1) * 193;
        const float* xr2 = xs + (tg * 4 + 2) * 193;
        const float* xr3 = xs + (tg * 4 + 3) * 193;
        const float* wr  = ws + j * 193;
        #pragma unroll 4
        for (int k = 0; k < 192; k++) {
            float wv = wr[k];
            acc0 += xr0[k] * wv;
            acc1 += xr1[k] * wv;
            acc2 += xr2[k] * wv;
            acc3 += xr3[k] * wv;
        }
        __syncthreads();
    }
    float bj = bias[j0 + j];
    #pragma unroll
    for (int i = 0; i < 4; i++) {
        int patch = pt0 + tg * 4 + i;
        int b = patch / ntok, t = patch % ntok;
        float acc = (i == 0) ? acc0 : (i == 1) ? acc1 : (i == 2) ? acc2 : acc3;
        hidden[((size_t)b * LL + tok_off + t) * DM + j0 + j] =
            acc + bj + pos[(size_t)t * DM + j0 + j];
    }
}

// ---------- fused conv+silu -> x_proj -> dt. block = 16 tokens ----------
__global__ __launch_bounds__(256) void cpd_kernel(const float* __restrict__ xz,
                                                  const float* __restrict__ cw,
                                                  const float* __restrict__ cb,
                                                  const float* __restrict__ xpw,
                                                  const float* __restrict__ dtw,
                                                  const float* __restrict__ dtbias,
                                                  float* __restrict__ xc,
                                                  float* __restrict__ dbl,
                                                  float* __restrict__ dtbuf,
                                                  int layer) {
    __shared__ float sxz[19 * 384];   // x-half of xz, tokens t0-3 .. t0+15
    __shared__ float sxc[16 * 384];
    __shared__ float sdbl[16 * 44];
    int t0 = blockIdx.x * 16;
    int l0 = t0 % LL;
    for (int idx = threadIdx.x; idx < 19 * 384; idx += 256) {
        int r = idx / 384, d = idx % 384;
        int l = l0 - 3 + r;
        sxz[idx] = (l >= 0) ? xz[(size_t)(t0 - 3 + r) * 768 + d] : 0.f;
    }
    __syncthreads();
    const float* cwl = cw + (size_t)layer * DI * DC;
    const float* cbl = cb + (size_t)layer * DI;
    for (int idx = threadIdx.x; idx < 16 * 384; idx += 256) {
        int tt = idx / 384, d = idx % 384;
        float a = cbl[d];
        #pragma unroll
        for (int k = 0; k < 4; k++)
            a += cwl[d * 4 + k] * sxz[(tt + k) * 384 + d];
        a = siluf(a);
        sxc[idx] = a;
        xc[(size_t)(t0 + tt) * DI + d] = a;
    }
    __syncthreads();
    const float* xpl = xpw + (size_t)layer * 44 * 384;
    for (int idx = threadIdx.x; idx < 16 * 44; idx += 256) {
        int tt = idx / 44, jj = idx % 44;
        const float* wr = xpl + (size_t)jj * 384;
        const float* xr = sxc + tt * 384;
        float a = 0.f;
        for (int k = 0; k < 384; k += 4)
            a += xr[k] * wr[k] + xr[k+1] * wr[k+1] + xr[k+2] * wr[k+2] + xr[k+3] * wr[k+3];
        sdbl[idx] = a;
        dbl[(size_t)(t0 + tt) * 44 + jj] = a;
    }
    __syncthreads();
    const float* dwl = dtw + (size_t)layer * DI * DTR;
    const float* dbb = dtbias + (size_t)layer * DI;
    for (int idx = threadIdx.x; idx < 16 * 384; idx += 256) {
        int tt = idx / 384, d = idx % 384;
        float a = dbb[d];
        const float* xr = sdbl + tt * 44;
        const float* wr = dwl + d * 12;
        #pragma unroll
        for (int r = 0; r < 12; r++) a += xr[r] * wr[r];
        dtbuf[(size_t)(t0 + tt) * DI + d] = softplusf(a);
    }
}

// ---------- chunked scan phase A: per-chunk (prod dA, local h) ----------
// group g = (b*NC + c)*DI + d ; 16 lanes = states
__global__ __launch_bounds__(256) void scanA(const float* __restrict__ dt,
                                             const float* __restrict__ xc,
                                             const float* __restrict__ dbl,
                                             const float* __restrict__ A_log,
                                             float* __restrict__ Pout,
                                             float* __restrict__ Hout,
                                             size_t aoff) {
    int g = blockIdx.x * 16 + (threadIdx.x >> 4);
    int n = threadIdx.x & 15;
    int d = g % DI;
    int bc = g / DI;
    int b = bc / NC, c = bc % NC;
    float A = -expf(A_log[aoff + (size_t)d * DS + n]);
    float h = 0.f, P = 1.f;
    int tbase = b * LL + c * LC;
    for (int l = 0; l < LC; l++) {
        size_t t = (size_t)tbase + l;
        float dtv = dt[t * DI + d];
        float xcv = xc[t * DI + d];
        float Bv = dbl[t * 44 + DTR + n];
        float dA = __expf(dtv * A);
        h = dA * h + dtv * Bv * xcv;
        P *= dA;
    }
    Pout[(size_t)g * 16 + n] = P;
    Hout[(size_t)g * 16 + n] = h;
}

// ---------- chunked scan phase C: fold prefix, replay, emit y. y aliases xc ----------
__global__ __launch_bounds__(256) void scanC(const float* __restrict__ dt,
                                             const float* xc,
                                             const float* __restrict__ dbl,
                                             const float* __restrict__ xz,
                                             const float* __restrict__ A_log,
                                             const float* __restrict__ Dskip,
                                             const float* __restrict__ Pin,
                                             const float* __restrict__ Hin,
                                             float* y,
                                             size_t aoff, size_t doff) {
    int g = blockIdx.x * 16 + (threadIdx.x >> 4);
    int n = threadIdx.x & 15;
    int d = g % DI;
    int bc = g / DI;
    int b = bc / NC, c = bc % NC;
    float h = 0.f;
    for (int cc = 0; cc < c; cc++) {
        size_t gi = ((size_t)(b * NC + cc) * DI + d) * 16 + n;
        h = Pin[gi] * h + Hin[gi];
    }
    float A = -expf(A_log[aoff + (size_t)d * DS + n]);
    float Dv = Dskip[doff + d];
    int tbase = b * LL + c * LC;
    for (int l = 0; l < LC; l++) {
        size_t t = (size_t)tbase + l;
        float dtv = dt[t * DI + d];
        float xcv = xc[t * DI + d];
        float Bv = dbl[t * 44 + DTR + n];
        float Cv = dbl[t * 44 + DTR + DS + n];
        h = __expf(dtv * A) * h + dtv * Bv * xcv;
        float p = h * Cv;
        p += __shfl_xor(p, 1);
        p += __shfl_xor(p, 2);
        p += __shfl_xor(p, 4);
        p += __shfl_xor(p, 8);
        if (n == 0) {
            float zg = xz[t * (2 * DI) + DI + d];
            y[t * DI + d] = (p + xcv * Dv) * siluf(zg);
        }
    }
}

// ---------- final: LN(residual + hidden) -> float32 ----------
__global__ __launch_bounds__(64) void final_kernel(const float* __restrict__ hidden,
                                                   const float* __restrict__ residual,
                                                   const float* __restrict__ w,
                                                   const float* __restrict__ bias,
                                                   float* __restrict__ out) {
    int t = blockIdx.x;
    int lane = threadIdx.x;
    size_t base = (size_t)t * DM;
    float a = residual[base + lane]       + hidden[base + lane];
    float b = residual[base + 64 + lane]  + hidden[base + 64 + lane];
    float c = residual[base + 128 + lane] + hidden[base + 128 + lane];
    float mu = wave_sum64(a + b + c) * (1.f / 192.f);
    float va = a - mu, vb = b - mu, vc = c - mu;
    float var = wave_sum64(va * va + vb * vb + vc * vc) * (1.f / 192.f);
    float inv = rsqrtf(var + EPSV);
    out[base + lane]       = va * inv * w[lane]       + bias[lane];
    out[base + 64 + lane]  = vb * inv * w[64 + lane]  + bias[64 + lane];
    out[base + 128 + lane] = vc * inv * w[128 + lane] + bias[128 + lane];
}

extern "C" void kernel_launch(void* const* d_in, const int* in_sizes, int n_in,
                              void* d_out, int out_size, void* d_ws, size_t ws_size,
                              hipStream_t stream) {
    const float* x_img   = (const float*)d_in[0];
    const float* z_img   = (const float*)d_in[1];
    const float* patch_w = (const float*)d_in[2];
    const float* patch_b = (const float*)d_in[3];
    const float* pos_x   = (const float*)d_in[4];
    const float* pos_z   = (const float*)d_in[5];
    const float* ln_w    = (const float*)d_in[6];
    const float* ln_b    = (const float*)d_in[7];
    const float* in_w    = (const float*)d_in[8];
    const float* conv_w  = (const float*)d_in[9];
    const float* conv_b  = (const float*)d_in[10];
    const float* xproj_w = (const float*)d_in[11];
    const float* dt_w    = (const float*)d_in[12];
    const float* dt_b    = (const float*)d_in[13];
    const float* A_log   = (const float*)d_in[14];
    const float* D_skip  = (const float*)d_in[15];
    const float* out_w   = (const float*)d_in[16];
    const float* fnorm_w = (const float*)d_in[17];
    const float* fnorm_b = (const float*)d_in[18];

    // ws layout (floats), ~46.5 MB total (<52 MB proven):
    float* hidden   = (float*)d_ws;                         // NT*DM
    float* residual = hidden   + (size_t)NT * DM;           // NT*DM
    float* xz       = residual + (size_t)NT * DM;           // NT*768
    float* xc       = xz       + (size_t)NT * 2 * DI;       // NT*DI
    float* dbl      = xc       + (size_t)NT * DI;           // NT*44
    float* dtbuf    = dbl      + (size_t)NT * 44;           // NT*DI
    float* scanP    = dtbuf    + (size_t)NT * DI;           // BB*NC*DI*16
    float* scanH    = scanP    + (size_t)BB * NC * DI * 16; // BB*NC*DI*16
    float* hn       = hidden;   // alias (read-before-write per thread)
    float* yb       = xc;       // alias (read-before-write per step)

    zero_kernel<<<(NT * DM + 255) / 256, 256, 0, stream>>>(residual, NT * DM);

    // z-first concat: z tokens 0..63, x tokens 64..319
    {
        dim3 gx(BB * NX / 16, 3), gz(BB * NZ / 16, 3);
        patch_gemm<<<gx, 256, 0, stream>>>(x_img, patch_w, patch_b, pos_x,
                                           hidden, 16, NZ);
        patch_gemm<<<gz, 256, 0, stream>>>(z_img, patch_w, patch_b, pos_z,
                                           hidden, 8, 0);
    }

    const int scan_blocks = BB * NC * DI / 16;   // 3072
    for (int i = 0; i < DEPTH; i++) {
        addnorm_kernel<<<NT, 64, 0, stream>>>(
            hidden, residual, hn, ln_w, ln_b, (size_t)i * DM);
        {
            dim3 g(NT / 16, 12);
            gemm_lds<192, 192><<<g, 256, 0, stream>>>(
                hn, in_w, (size_t)i * 768 * 192, xz, 768);
        }
        cpd_kernel<<<NT / 16, 256, 0, stream>>>(
            xz, conv_w, conv_b, xproj_w, dt_w, dt_b, xc, dbl, dtbuf, i);
        scanA<<<scan_blocks, 256, 0, stream>>>(
            dtbuf, xc, dbl, A_log, scanP, scanH, (size_t)i * DI * DS);
        scanC<<<scan_blocks, 256, 0, stream>>>(
            dtbuf, xc, dbl, xz, A_log, D_skip, scanP, scanH, yb,
            (size_t)i * DI * DS, (size_t)i * DI);
        {
            dim3 g(NT / 16, 3);
            gemm_lds<384, 192><<<g, 256, 0, stream>>>(
                yb, out_w, (size_t)i * 192 * 384, hidden, 192);
        }
    }

    final_kernel<<<NT, 64, 0, stream>>>(hidden, residual, fnorm_w, fnorm_b,
                                        (float*)d_out);
}